// Round 3
// baseline (2298.162 us; speedup 1.0000x reference)
//
#include <hip/hip_runtime.h>

#define HD   1024      // hidden
#define G3   3072      // 3*H
#define ED   512       // embed
#define ZD   64        // latent dim (z)
#define VV   50257     // vocab
#define TT   64        // steps
#define BT   512

// ws layout (float offsets)
#define OFF_HINIT 0
#define OFF_HALL  1024
#define OFF_HALLT 66560      // 1024 + 64*1024
#define OFF_GI    132096     // + 1024*64
#define OFF_GMAX  135168     // + 3072
#define OFF_GSUM  135232
#define OFF_GTOK  135296

// ---------------- K0: h0 = z@Wdec + bdec ; gi = Wih@eos + bih ----------------
__global__ __launch_bounds__(BT) void k_init(
    const float* __restrict__ z,    const float* __restrict__ eos,
    const float* __restrict__ Wih,  const float* __restrict__ bih,
    const float* __restrict__ Wdec, const float* __restrict__ bdec,
    float* __restrict__ ws)
{
    const int tid = threadIdx.x;
    const int b   = blockIdx.x;
    float* h_init = ws + OFF_HINIT;
    float* gi     = ws + OFF_GI;

    if (b == 384) {
        #pragma unroll
        for (int rep = 0; rep < 2; ++rep) {
            int j = tid + rep * BT;          // 0..1023
            float acc = bdec[j];
            #pragma unroll
            for (int i = 0; i < ZD; ++i)
                acc = fmaf(z[i], Wdec[i * HD + j], acc);   // Wdec is (64,1024)
            h_init[j] = acc;
        }
    } else {
        const int gtid = b * BT + tid;
        const int w    = gtid >> 6;          // 0..3071
        const int lane = tid & 63;
        const float* wp = Wih + (size_t)w * ED + lane;
        float d = 0.f;
        #pragma unroll
        for (int i = 0; i < 8; ++i) d = fmaf(wp[i * 64], eos[lane + i * 64], d);
        #pragma unroll
        for (int off = 32; off; off >>= 1) d += __shfl_xor(d, off, 64);
        if (lane == 0) gi[w] = d + bih[w];
    }
}

// ---------------- K_step: one GRU step, wave-per-output-row ----------------
__global__ __launch_bounds__(BT) void k_step(
    const float* __restrict__ Whh, const float* __restrict__ bhh,
    float* __restrict__ ws, int t)
{
    const int tid  = threadIdx.x;
    const int gtid = blockIdx.x * BT + tid;
    const int w    = gtid >> 6;      // 0..1023 (grid = 128 blocks exactly)
    const int lane = tid & 63;

    float* h_init = ws + OFF_HINIT;
    float* h_all  = ws + OFF_HALL;
    float* h_allT = ws + OFF_HALLT;
    const float* gi = ws + OFF_GI;

    const float* hp = (t == 0) ? h_init : (h_all + (size_t)(t - 1) * HD);
    const float* r0 = Whh + (size_t)w * HD + lane;
    const float* r1 = Whh + (size_t)(w + HD) * HD + lane;
    const float* r2 = Whh + (size_t)(w + 2 * HD) * HD + lane;

    float d0 = 0.f, d1 = 0.f, d2 = 0.f;
    #pragma unroll
    for (int i = 0; i < 16; ++i) {
        float hv = hp[lane + i * 64];
        d0 = fmaf(r0[i * 64], hv, d0);
        d1 = fmaf(r1[i * 64], hv, d1);
        d2 = fmaf(r2[i * 64], hv, d2);
    }
    #pragma unroll
    for (int off = 32; off; off >>= 1) {
        d0 += __shfl_xor(d0, off, 64);
        d1 += __shfl_xor(d1, off, 64);
        d2 += __shfl_xor(d2, off, 64);
    }
    if (lane == 0) {
        float ghr = d0 + bhh[w];
        float ghz = d1 + bhh[w + HD];
        float ghn = d2 + bhh[w + 2 * HD];
        float r = 1.f / (1.f + expf(-(gi[w] + ghr)));
        float u = 1.f / (1.f + expf(-(gi[w + HD] + ghz)));
        float n = tanhf(gi[w + 2 * HD] + r * ghn);
        float hn = (1.f - u) * n + u * hp[w];
        h_all[(size_t)t * HD + w]  = hn;
        h_allT[(size_t)w * TT + t] = hn;
    }
}

// ---------------- K1: logits = h_all @ Wv + bv  (written raw into out) ----------------
#define FMA4(ACC, S) do { ACC.x = fmaf(w4.x,(S),ACC.x); ACC.y = fmaf(w4.y,(S),ACC.y); \
                          ACC.z = fmaf(w4.z,(S),ACC.z); ACC.w = fmaf(w4.w,(S),ACC.w); } while(0)

__global__ __launch_bounds__(BT, 4) void k_gemm(
    const float* __restrict__ Wv, const float* __restrict__ bv,
    const float* __restrict__ hT,         // h_allT: [k=1024][t=64]
    float* __restrict__ out)
{
    const int tid  = threadIdx.x;
    const int gtid = blockIdx.x * BT + tid;
    const int kp = tid & 3;                 // k-quarter (256 k each)
    const int tq = (tid >> 2) & 3;          // t-quarter (16 t each)
    const int t0 = tq << 4;
    const int vg = gtid >> 4;               // 0..12575
    const int v0 = vg << 2;                 // 0..50300
    const bool fullv = (v0 + 3 < VV);
    const bool vx = (v0 < VV);

    __shared__ __align__(16) float sh_hS[2][4368];   // [kp:4][kk:16 x 17 f4][t4 pad]

    float4 acc[16];
    #pragma unroll
    for (int i = 0; i < 16; ++i) acc[i] = make_float4(0.f, 0.f, 0.f, 0.f);

    float* shS = &sh_hS[0][0];
    auto stage = [&](int c, int bufsel) {
        float4* dst = (float4*)(shS + bufsel * 4368);
        const float4* src = (const float4*)hT;       // f4 index = k*16 + t4
        #pragma unroll
        for (int jj = 0; jj < 2; ++jj) {
            int f4 = jj * BT + tid;       // 0..1023
            int t4 = f4 & 15;
            int rest = f4 >> 4;           // 0..63
            int kk = rest & 15, kps = rest >> 4;
            int k = kps * 256 + c * 16 + kk;
            dst[kps * 273 + kk * 17 + t4] = src[k * 16 + t4];
        }
    };
    stage(0, 0);

    for (int c = 0; c < 16; ++c) {
        __syncthreads();
        if (c < 15) stage(c + 1, (c + 1) & 1);
        const float* shbuf = shS + (c & 1) * 4368 + kp * 1092 + t0;
        const float* wrow = Wv + (size_t)(kp * 256 + c * 16) * VV + v0;
        #pragma unroll
        for (int kk = 0; kk < 16; ++kk) {
            const float* wp = wrow + (size_t)kk * VV;
            float4 w4;
            if (fullv) { w4.x = wp[0]; w4.y = wp[1]; w4.z = wp[2]; w4.w = wp[3]; }
            else { w4.x = vx ? wp[0] : 0.f; w4.y = 0.f; w4.z = 0.f; w4.w = 0.f; }
            const float* sf = shbuf + kk * 68;
            float4 ha = ((const float4*)sf)[0];
            float4 hb = ((const float4*)sf)[1];
            float4 hc = ((const float4*)sf)[2];
            float4 hd = ((const float4*)sf)[3];
            FMA4(acc[0],  ha.x); FMA4(acc[1],  ha.y); FMA4(acc[2],  ha.z); FMA4(acc[3],  ha.w);
            FMA4(acc[4],  hb.x); FMA4(acc[5],  hb.y); FMA4(acc[6],  hb.z); FMA4(acc[7],  hb.w);
            FMA4(acc[8],  hc.x); FMA4(acc[9],  hc.y); FMA4(acc[10], hc.z); FMA4(acc[11], hc.w);
            FMA4(acc[12], hd.x); FMA4(acc[13], hd.y); FMA4(acc[14], hd.z); FMA4(acc[15], hd.w);
        }
    }

    // combine k-quarters (butterfly over kp bits 0-1)
    #pragma unroll
    for (int i = 0; i < 16; ++i) {
        float4 a = acc[i];
        a.x += __shfl_xor(a.x, 1, 64); a.y += __shfl_xor(a.y, 1, 64);
        a.z += __shfl_xor(a.z, 1, 64); a.w += __shfl_xor(a.w, 1, 64);
        a.x += __shfl_xor(a.x, 2, 64); a.y += __shfl_xor(a.y, 2, 64);
        a.z += __shfl_xor(a.z, 2, 64); a.w += __shfl_xor(a.w, 2, 64);
        acc[i] = a;
    }

    if (kp == 0) {
        float bx = 0.f, by = 0.f, bz = 0.f, bw = 0.f;
        if (fullv) { bx = bv[v0]; by = bv[v0 + 1]; bz = bv[v0 + 2]; bw = bv[v0 + 3]; }
        else if (vx) bx = bv[v0];
        #pragma unroll
        for (int tt = 0; tt < 16; ++tt) {
            float4 a = acc[tt];
            float* op = out + (size_t)(t0 + tt) * VV + v0;
            if (fullv) { op[0] = a.x + bx; op[1] = a.y + by; op[2] = a.z + bz; op[3] = a.w + bw; }
            else if (vx) { op[0] = a.x + bx; }
        }
    }
}

// ---------------- K2: per-row max/argmax (first-index ties) + sum(exp) ----------------
__global__ __launch_bounds__(1024) void k_rowstat(
    const float* __restrict__ out,
    float* __restrict__ gMax, float* __restrict__ gSum, int* __restrict__ gTok)
{
    const int t   = blockIdx.x;
    const int tid = threadIdx.x;
    const float* row = out + (size_t)t * VV;

    __shared__ float sm[1024];
    __shared__ int   si[1024];

    float m = -3.4e38f; int mi = 0;
    for (int i = tid; i < VV; i += 1024) {
        float v = row[i];
        if (v > m) { m = v; mi = i; }          // ascending scan -> first max per thread
    }
    sm[tid] = m; si[tid] = mi;
    __syncthreads();
    for (int s = 512; s; s >>= 1) {
        if (tid < s) {
            float om = sm[tid + s]; int oi = si[tid + s];
            if (om > sm[tid] || (om == sm[tid] && oi < si[tid])) { sm[tid] = om; si[tid] = oi; }
        }
        __syncthreads();
    }
    float mrow = sm[0];
    int   irow = si[0];
    __syncthreads();

    float s = 0.f;
    for (int i = tid; i < VV; i += 1024) s += expf(row[i] - mrow);
    sm[tid] = s;
    __syncthreads();
    for (int st = 512; st; st >>= 1) {
        if (tid < st) sm[tid] += sm[tid + st];
        __syncthreads();
    }
    if (tid == 0) { gMax[t] = mrow; gSum[t] = sm[0]; gTok[t] = irow; }
}

// ---------------- K3: log_p = logit - lz ; write tokens ----------------
__global__ __launch_bounds__(BT) void k_final(
    const float* __restrict__ gMax, const float* __restrict__ gSum,
    const int* __restrict__ gTok, float* __restrict__ out)
{
    __shared__ float s_lz[TT];
    const int tid  = threadIdx.x;
    const int gtid = blockIdx.x * BT + tid;
    if (tid < TT) s_lz[tid] = gMax[tid] + logf(gSum[tid]);
    __syncthreads();

    const int total  = TT * VV;          // 3216448
    const int stride = 393 * BT;         // 201216
    #pragma unroll
    for (int r = 0; r < 16; ++r) {
        int idx = gtid + r * stride;
        if (idx < total) {
            int t = idx / VV;
            out[idx] = out[idx] - s_lz[t];
        }
    }
    if (gtid < TT) out[(size_t)total + gtid] = (float)gTok[gtid];
}

extern "C" void kernel_launch(void* const* d_in, const int* in_sizes, int n_in,
                              void* d_out, int out_size, void* d_ws, size_t ws_size,
                              hipStream_t stream) {
    (void)in_sizes; (void)n_in; (void)out_size; (void)ws_size;
    const float* z    = (const float*)d_in[0];
    const float* eos  = (const float*)d_in[1];
    const float* Wih  = (const float*)d_in[2];
    const float* Whh  = (const float*)d_in[3];
    const float* bih  = (const float*)d_in[4];
    const float* bhh  = (const float*)d_in[5];
    const float* Wdec = (const float*)d_in[6];
    const float* bdec = (const float*)d_in[7];
    const float* Wv   = (const float*)d_in[8];
    const float* bv   = (const float*)d_in[9];
    float* out = (float*)d_out;
    float* ws  = (float*)d_ws;

    hipLaunchKernelGGL(k_init, dim3(385), dim3(BT), 0, stream,
                       z, eos, Wih, bih, Wdec, bdec, ws);
    for (int t = 0; t < TT; ++t)
        hipLaunchKernelGGL(k_step, dim3(128), dim3(BT), 0, stream, Whh, bhh, ws, t);
    hipLaunchKernelGGL(k_gemm, dim3(393), dim3(BT), 0, stream,
                       Wv, bv, ws + OFF_HALLT, out);
    hipLaunchKernelGGL(k_rowstat, dim3(TT), dim3(1024), 0, stream,
                       out, ws + OFF_GMAX, ws + OFF_GSUM, (int*)(ws + OFF_GTOK));
    hipLaunchKernelGGL(k_final, dim3(393), dim3(BT), 0, stream,
                       ws + OFF_GMAX, ws + OFF_GSUM, (const int*)(ws + OFF_GTOK), out);
}

// Round 5
// 841.852 us; speedup vs baseline: 2.7299x; 2.7299x over previous
//
#include <hip/hip_runtime.h>

#define HD   1024      // hidden
#define G3   3072      // 3*H
#define ED   512       // embed
#define ZD   64        // latent dim (z)
#define VV   50257     // vocab
#define TT   64        // steps
#define BT   512

// ws layout (float offsets)
#define OFF_HINIT 0
#define OFF_HALL  1024
#define OFF_HALLT 66560      // 1024 + 64*1024
#define OFF_GI    132096     // + 1024*64
#define OFF_PMAX  135168     // 256 floats  [t][q]
#define OFF_PIDX  135424     // 256 ints
#define OFF_PSUM  135680     // 256 floats

// ---------------- K0: h0 = z@Wdec + bdec ; gi = Wih@eos + bih ----------------
__global__ __launch_bounds__(BT) void k_init(
    const float* __restrict__ z,    const float* __restrict__ eos,
    const float* __restrict__ Wih,  const float* __restrict__ bih,
    const float* __restrict__ Wdec, const float* __restrict__ bdec,
    float* __restrict__ ws)
{
    const int tid = threadIdx.x;
    const int b   = blockIdx.x;
    float* h_init = ws + OFF_HINIT;
    float* gi     = ws + OFF_GI;

    if (b == 384) {
        #pragma unroll
        for (int rep = 0; rep < 2; ++rep) {
            int j = tid + rep * BT;          // 0..1023
            float acc = bdec[j];
            #pragma unroll
            for (int i = 0; i < ZD; ++i)
                acc = fmaf(z[i], Wdec[i * HD + j], acc);   // Wdec is (64,1024)
            h_init[j] = acc;
        }
    } else {
        const int gtid = b * BT + tid;
        const int w    = gtid >> 6;          // 0..3071
        const int lane = tid & 63;
        const float* wp = Wih + (size_t)w * ED + lane;
        float d = 0.f;
        #pragma unroll
        for (int i = 0; i < 8; ++i) d = fmaf(wp[i * 64], eos[lane + i * 64], d);
        #pragma unroll
        for (int off = 32; off; off >>= 1) d += __shfl_xor(d, off, 64);
        if (lane == 0) gi[w] = d + bih[w];
    }
}

// ---------------- K_step: one GRU step, wave-per-output-row ----------------
__global__ __launch_bounds__(BT) void k_step(
    const float* __restrict__ Whh, const float* __restrict__ bhh,
    float* __restrict__ ws, int t)
{
    const int tid  = threadIdx.x;
    const int gtid = blockIdx.x * BT + tid;
    const int w    = gtid >> 6;      // 0..1023 (grid = 128 blocks exactly)
    const int lane = tid & 63;

    float* h_init = ws + OFF_HINIT;
    float* h_all  = ws + OFF_HALL;
    float* h_allT = ws + OFF_HALLT;
    const float* gi = ws + OFF_GI;

    const float* hp = (t == 0) ? h_init : (h_all + (size_t)(t - 1) * HD);
    const float* r0 = Whh + (size_t)w * HD + lane;
    const float* r1 = Whh + (size_t)(w + HD) * HD + lane;
    const float* r2 = Whh + (size_t)(w + 2 * HD) * HD + lane;

    float d0 = 0.f, d1 = 0.f, d2 = 0.f;
    #pragma unroll
    for (int i = 0; i < 16; ++i) {
        float hv = hp[lane + i * 64];
        d0 = fmaf(r0[i * 64], hv, d0);
        d1 = fmaf(r1[i * 64], hv, d1);
        d2 = fmaf(r2[i * 64], hv, d2);
    }
    #pragma unroll
    for (int off = 32; off; off >>= 1) {
        d0 += __shfl_xor(d0, off, 64);
        d1 += __shfl_xor(d1, off, 64);
        d2 += __shfl_xor(d2, off, 64);
    }
    if (lane == 0) {
        float ghr = d0 + bhh[w];
        float ghz = d1 + bhh[w + HD];
        float ghn = d2 + bhh[w + 2 * HD];
        float r = 1.f / (1.f + expf(-(gi[w] + ghr)));
        float u = 1.f / (1.f + expf(-(gi[w + HD] + ghz)));
        float n = tanhf(gi[w + 2 * HD] + r * ghn);
        float hn = (1.f - u) * n + u * hp[w];
        h_all[(size_t)t * HD + w]  = hn;
        h_allT[(size_t)w * TT + t] = hn;
    }
}

// ---------------- K1: logits = h_all @ Wv + bv  (raw, into out) ----------------
// lane layout: kp = tid[0:1] (k-quarter), vg = tid[2:5] (16 v-groups/block),
//              tq = tid[6:8] (8 t-groups of 8, wave-uniform)
// acc: 8 t-rows x 4 v-cols = 32 VGPRs. No occupancy forcing -> no spills.
#define FMA4(ACC, S) do { ACC.x = fmaf(w4.x,(S),ACC.x); ACC.y = fmaf(w4.y,(S),ACC.y); \
                          ACC.z = fmaf(w4.z,(S),ACC.z); ACC.w = fmaf(w4.w,(S),ACC.w); } while(0)

__global__ __launch_bounds__(BT) void k_gemm(
    const float* __restrict__ Wv, const float* __restrict__ bv,
    const float* __restrict__ hT,         // h_allT: [k=1024][t=64]
    float* __restrict__ out)
{
    const int tid = threadIdx.x;
    const int kp  = tid & 3;                 // k-quarter (256 k each)
    const int vgl = (tid >> 2) & 15;         // local v-group
    const int tq  = tid >> 6;                // 0..7, wave-uniform
    const int t0  = tq << 3;
    const int vg  = blockIdx.x * 16 + vgl;   // 0..12575
    const int v0  = vg << 2;                 // 0..50300
    const bool fullv = (v0 + 3 < VV);
    const bool vx = (v0 < VV);

    __shared__ __align__(16) float sh_hS[2][4368];   // [kp:4][kk:16 x 17 f4]

    float4 acc[8];
    #pragma unroll
    for (int i = 0; i < 8; ++i) acc[i] = make_float4(0.f, 0.f, 0.f, 0.f);

    float* shS = &sh_hS[0][0];
    auto stage = [&](int c, int bufsel) {
        float4* dst = (float4*)(shS + bufsel * 4368);
        const float4* src = (const float4*)hT;       // f4 index = k*16 + t4
        #pragma unroll
        for (int jj = 0; jj < 2; ++jj) {
            int f4 = jj * BT + tid;       // 0..1023
            int t4 = f4 & 15;
            int rest = f4 >> 4;           // 0..63
            int kk = rest & 15, kps = rest >> 4;
            int k = kps * 256 + c * 16 + kk;
            dst[kps * 273 + kk * 17 + t4] = src[k * 16 + t4];
        }
    };
    stage(0, 0);

    for (int c = 0; c < 16; ++c) {
        __syncthreads();
        if (c < 15) stage(c + 1, (c + 1) & 1);
        const float* shbuf = shS + (c & 1) * 4368 + kp * 1092 + t0;
        const float* wrow = Wv + (size_t)(kp * 256 + c * 16) * VV + v0;
        #pragma unroll
        for (int kk = 0; kk < 16; ++kk) {
            const float* wp = wrow + (size_t)kk * VV;
            float4 w4;
            if (fullv) { w4.x = wp[0]; w4.y = wp[1]; w4.z = wp[2]; w4.w = wp[3]; }
            else { w4.x = vx ? wp[0] : 0.f; w4.y = 0.f; w4.z = 0.f; w4.w = 0.f; }
            const float* sf = shbuf + kk * 68;
            float4 ha = ((const float4*)sf)[0];
            float4 hb = ((const float4*)sf)[1];
            FMA4(acc[0], ha.x); FMA4(acc[1], ha.y); FMA4(acc[2], ha.z); FMA4(acc[3], ha.w);
            FMA4(acc[4], hb.x); FMA4(acc[5], hb.y); FMA4(acc[6], hb.z); FMA4(acc[7], hb.w);
        }
    }

    // combine k-quarters (butterfly over kp bits 0-1)
    #pragma unroll
    for (int i = 0; i < 8; ++i) {
        float4 a = acc[i];
        a.x += __shfl_xor(a.x, 1, 64); a.y += __shfl_xor(a.y, 1, 64);
        a.z += __shfl_xor(a.z, 1, 64); a.w += __shfl_xor(a.w, 1, 64);
        a.x += __shfl_xor(a.x, 2, 64); a.y += __shfl_xor(a.y, 2, 64);
        a.z += __shfl_xor(a.z, 2, 64); a.w += __shfl_xor(a.w, 2, 64);
        acc[i] = a;
    }

    if (kp == 0) {
        float bx = 0.f, by = 0.f, bz = 0.f, bw = 0.f;
        if (fullv) { bx = bv[v0]; by = bv[v0 + 1]; bz = bv[v0 + 2]; bw = bv[v0 + 3]; }
        else if (vx) bx = bv[v0];
        #pragma unroll
        for (int tt = 0; tt < 8; ++tt) {
            float4 a = acc[tt];
            float* op = out + (size_t)(t0 + tt) * VV + v0;
            if (fullv) { op[0] = a.x + bx; op[1] = a.y + by; op[2] = a.z + bz; op[3] = a.w + bw; }
            else if (vx) { op[0] = a.x + bx; }
        }
    }
}

// ---------------- K2: per-(row,quarter) max/argmax (first-index ties) + sum(exp) ----------------
#define RSB 512
#define QCH 12576      // ceil(50257/4) rounded to x16
__global__ __launch_bounds__(RSB) void k_rowstat(
    const float* __restrict__ out,
    float* __restrict__ pMax, int* __restrict__ pIdx, float* __restrict__ pSum)
{
    const int t   = blockIdx.x >> 2;
    const int q   = blockIdx.x & 3;
    const int tid = threadIdx.x;
    const int start = q * QCH;
    const int end   = (start + QCH < VV) ? (start + QCH) : VV;
    const float* row = out + (size_t)t * VV;

    __shared__ float sm[RSB];
    __shared__ int   si[RSB];

    float m = -3.4e38f; int mi = start;
    for (int i = start + tid; i < end; i += RSB) {
        float v = row[i];
        if (v > m) { m = v; mi = i; }          // ascending -> first max per thread
    }
    sm[tid] = m; si[tid] = mi;
    __syncthreads();
    for (int s = RSB / 2; s; s >>= 1) {
        if (tid < s) {
            float om = sm[tid + s]; int oi = si[tid + s];
            if (om > sm[tid] || (om == sm[tid] && oi < si[tid])) { sm[tid] = om; si[tid] = oi; }
        }
        __syncthreads();
    }
    const float M = sm[0];
    const int   I = si[0];
    __syncthreads();

    float s = 0.f;
    for (int i = start + tid; i < end; i += RSB) s += expf(row[i] - M);
    sm[tid] = s;
    __syncthreads();
    for (int st = RSB / 2; st; st >>= 1) {
        if (tid < st) sm[tid] += sm[tid + st];
        __syncthreads();
    }
    if (tid == 0) { pMax[blockIdx.x] = M; pIdx[blockIdx.x] = I; pSum[blockIdx.x] = sm[0]; }
}

// ---------------- K3: combine partials; log_p = logit - lz ; write tokens ----------------
__global__ __launch_bounds__(BT) void k_final(
    const float* __restrict__ pMax, const int* __restrict__ pIdx,
    const float* __restrict__ pSum, float* __restrict__ out)
{
    __shared__ float s_lz[TT];
    const int tid  = threadIdx.x;
    const int gtid = blockIdx.x * BT + tid;
    if (tid < TT) {
        float M = -3.4e38f; int I = 0;
        #pragma unroll
        for (int q = 0; q < 4; ++q) {            // ascending q -> first-occurrence ties
            float m = pMax[tid * 4 + q];
            if (m > M) { M = m; I = pIdx[tid * 4 + q]; }
        }
        float S = 0.f;
        #pragma unroll
        for (int q = 0; q < 4; ++q)
            S += pSum[tid * 4 + q] * expf(pMax[tid * 4 + q] - M);
        s_lz[tid] = M + logf(S);
        if (blockIdx.x == 0) out[(size_t)TT * VV + tid] = (float)I;
    }
    __syncthreads();

    const int total  = TT * VV;          // 3216448
    const int stride = 393 * BT;         // 201216
    #pragma unroll
    for (int r = 0; r < 16; ++r) {
        int idx = gtid + r * stride;
        if (idx < total) {
            int t = idx / VV;
            out[idx] = out[idx] - s_lz[t];
        }
    }
}

extern "C" void kernel_launch(void* const* d_in, const int* in_sizes, int n_in,
                              void* d_out, int out_size, void* d_ws, size_t ws_size,
                              hipStream_t stream) {
    (void)in_sizes; (void)n_in; (void)out_size; (void)ws_size;
    const float* z    = (const float*)d_in[0];
    const float* eos  = (const float*)d_in[1];
    const float* Wih  = (const float*)d_in[2];
    const float* Whh  = (const float*)d_in[3];
    const float* bih  = (const float*)d_in[4];
    const float* bhh  = (const float*)d_in[5];
    const float* Wdec = (const float*)d_in[6];
    const float* bdec = (const float*)d_in[7];
    const float* Wv   = (const float*)d_in[8];
    const float* bv   = (const float*)d_in[9];
    float* out = (float*)d_out;
    float* ws  = (float*)d_ws;

    hipLaunchKernelGGL(k_init, dim3(385), dim3(BT), 0, stream,
                       z, eos, Wih, bih, Wdec, bdec, ws);
    for (int t = 0; t < TT; ++t)
        hipLaunchKernelGGL(k_step, dim3(128), dim3(BT), 0, stream, Whh, bhh, ws, t);
    hipLaunchKernelGGL(k_gemm, dim3(786), dim3(BT), 0, stream,
                       Wv, bv, ws + OFF_HALLT, out);
    hipLaunchKernelGGL(k_rowstat, dim3(256), dim3(RSB), 0, stream,
                       out, ws + OFF_PMAX, (int*)(ws + OFF_PIDX), ws + OFF_PSUM);
    hipLaunchKernelGGL(k_final, dim3(393), dim3(BT), 0, stream,
                       ws + OFF_PMAX, (const int*)(ws + OFF_PIDX), ws + OFF_PSUM, out);
}